// Round 1
// baseline (983.937 us; speedup 1.0000x reference)
//
#include <hip/hip_runtime.h>
#include <math.h>

// Problem constants
#define NPX   1048576      // 1024*1024
#define TD    1025         // tex_eval spatial dim
#define NK    512          // 32 ic * 4 * 4
// ws layout: [0, 32KB)  filt_t  fp32 [k][oc]  (k = ic*16 + ky*4 + kx)
//            [32KB, ..) tex     bf16 [y][x][c], (TD*TD*16) ushorts

__device__ __forceinline__ unsigned short f2bf(float f) {
    unsigned u = __float_as_uint(f);
    unsigned r = (u + 0x7fffu + ((u >> 16) & 1u)) >> 16;
    return (unsigned short)r;
}
__device__ __forceinline__ float bf2f(unsigned short s) {
    return __uint_as_float((unsigned)s << 16);
}

// ---------------- Stage 1: MLP -> conv filter (transposed layout) -------------
__global__ __launch_bounds__(256) void mlp_kernel(
    const float* __restrict__ expr,
    const float* __restrict__ W1, const float* __restrict__ b1,
    const float* __restrict__ W2, const float* __restrict__ b2,
    const float* __restrict__ W3, const float* __restrict__ b3,
    float* __restrict__ filt_t)
{
    __shared__ float sx[76];
    __shared__ float sh1[128];
    __shared__ float sh2[64];
    int t = threadIdx.x;
    if (t < 76) sx[t] = expr[t];
    __syncthreads();
    if (t < 128) {
        float a = b1[t];
        const float* w = W1 + t * 76;
        #pragma unroll 4
        for (int i = 0; i < 76; ++i) a += sx[i] * w[i];
        sh1[t] = a >= 0.f ? a : 0.02f * a;
    }
    __syncthreads();
    if (t < 64) {
        float a = b2[t];
        const float* w = W2 + t * 128;
        #pragma unroll 4
        for (int i = 0; i < 128; ++i) a += sh1[i] * w[i];
        sh2[t] = a >= 0.f ? a : 0.02f * a;
    }
    __syncthreads();
    int o = blockIdx.x * 256 + t;            // 0..8191
    float a = b3[o];
    const float* w = W3 + o * 64;
    #pragma unroll 4
    for (int i = 0; i < 64; ++i) a += sh2[i] * w[i];
    a = tanhf(a);
    int oc = o >> 9;                          // o / 512
    int k  = o & 511;                         // ic*16 + ky*4 + kx
    filt_t[k * 16 + oc] = a;
}

// ---------------- Stage 2: 4x4 conv, pad 2 -> tex (bf16, channel-last) -------
__global__ __launch_bounds__(256) void conv_kernel(
    const float* __restrict__ data,          // [32][1024][1024]
    const float* __restrict__ filt_t,        // [512][16]
    unsigned short* __restrict__ tex)        // [1025][1025][16] bf16
{
    __shared__ float sf[NK * 16];
    int tid = threadIdx.y * 64 + threadIdx.x;
    for (int i = tid; i < NK * 16; i += 256) sf[i] = filt_t[i];
    __syncthreads();

    int ox = blockIdx.x * 64 + threadIdx.x;
    int oy = blockIdx.y * 4 + threadIdx.y;
    if (ox >= TD || oy >= TD) return;

    float acc[16];
    #pragma unroll
    for (int c = 0; c < 16; ++c) acc[c] = 0.f;

    const float4* sf4 = (const float4*)sf;
    for (int ic = 0; ic < 32; ++ic) {
        const float* dch = data + ic * NPX;
        #pragma unroll
        for (int ky = 0; ky < 4; ++ky) {
            int yy = oy - 2 + ky;
            bool yok = ((unsigned)yy < 1024u);
            const float* drow = dch + yy * 1024;
            #pragma unroll
            for (int kx = 0; kx < 4; ++kx) {
                int xx = ox - 2 + kx;
                float v = (yok && ((unsigned)xx < 1024u)) ? drow[xx] : 0.f;
                int k = ic * 16 + ky * 4 + kx;
                float4 f0 = sf4[k * 4 + 0];
                float4 f1 = sf4[k * 4 + 1];
                float4 f2 = sf4[k * 4 + 2];
                float4 f3 = sf4[k * 4 + 3];
                acc[0]  += v * f0.x;  acc[1]  += v * f0.y;
                acc[2]  += v * f0.z;  acc[3]  += v * f0.w;
                acc[4]  += v * f1.x;  acc[5]  += v * f1.y;
                acc[6]  += v * f1.z;  acc[7]  += v * f1.w;
                acc[8]  += v * f2.x;  acc[9]  += v * f2.y;
                acc[10] += v * f2.z;  acc[11] += v * f2.w;
                acc[12] += v * f3.x;  acc[13] += v * f3.y;
                acc[14] += v * f3.z;  acc[15] += v * f3.w;
            }
        }
    }

    union { unsigned short s[16]; uint4 q[2]; } pk;
    #pragma unroll
    for (int c = 0; c < 16; ++c) pk.s[c] = f2bf(acc[c]);
    uint4* to = (uint4*)(tex + (size_t)(oy * TD + ox) * 16);
    to[0] = pk.q[0];
    to[1] = pk.q[1];
}

// ---------------- Stage 3: bilinear grid-sample (border pad) -----------------
__global__ __launch_bounds__(256) void sample_kernel(
    const float* __restrict__ uv,            // [2][1024][1024]
    const unsigned short* __restrict__ tex,  // [1025][1025][16] bf16
    float* __restrict__ out)                 // [16][1024][1024]
{
    int p = blockIdx.x * 256 + threadIdx.x;  // 0..NPX-1
    float x = uv[p];
    float y = uv[NPX + p];
    float ix = ((x + 1.0f) * 1025.0f - 1.0f) * 0.5f;
    float iy = ((y + 1.0f) * 1025.0f - 1.0f) * 0.5f;
    ix = fminf(fmaxf(ix, 0.0f), 1024.0f);
    iy = fminf(fmaxf(iy, 0.0f), 1024.0f);
    float fx0 = floorf(ix), fy0 = floorf(iy);
    float wx = ix - fx0, wy = iy - fy0;
    int x0 = (int)fx0, y0 = (int)fy0;
    int x1 = min(x0 + 1, 1024), y1 = min(y0 + 1, 1024);

    const uint4* t00 = (const uint4*)(tex + (size_t)(y0 * TD + x0) * 16);
    const uint4* t01 = (const uint4*)(tex + (size_t)(y0 * TD + x1) * 16);
    const uint4* t10 = (const uint4*)(tex + (size_t)(y1 * TD + x0) * 16);
    const uint4* t11 = (const uint4*)(tex + (size_t)(y1 * TD + x1) * 16);

    float w00 = (1.f - wx) * (1.f - wy);
    float w01 = wx * (1.f - wy);
    float w10 = (1.f - wx) * wy;
    float w11 = wx * wy;

    #pragma unroll
    for (int h = 0; h < 2; ++h) {
        uint4 a = t00[h], b = t01[h], c = t10[h], d = t11[h];
        const unsigned* au = (const unsigned*)&a;
        const unsigned* bu = (const unsigned*)&b;
        const unsigned* cu = (const unsigned*)&c;
        const unsigned* du = (const unsigned*)&d;
        #pragma unroll
        for (int q = 0; q < 4; ++q) {
            float a0 = bf2f((unsigned short)(au[q] & 0xffffu));
            float a1 = bf2f((unsigned short)(au[q] >> 16));
            float b0 = bf2f((unsigned short)(bu[q] & 0xffffu));
            float b1 = bf2f((unsigned short)(bu[q] >> 16));
            float c0 = bf2f((unsigned short)(cu[q] & 0xffffu));
            float c1 = bf2f((unsigned short)(cu[q] >> 16));
            float d0 = bf2f((unsigned short)(du[q] & 0xffffu));
            float d1 = bf2f((unsigned short)(du[q] >> 16));
            int ch = h * 8 + q * 2;
            float r0 = a0 * w00 + b0 * w01 + c0 * w10 + d0 * w11;
            float r1 = a1 * w00 + b1 * w01 + c1 * w10 + d1 * w11;
            out[(size_t)ch * NPX + p]       = r0;
            out[(size_t)(ch + 1) * NPX + p] = r1;
        }
    }
}

extern "C" void kernel_launch(void* const* d_in, const int* in_sizes, int n_in,
                              void* d_out, int out_size, void* d_ws, size_t ws_size,
                              hipStream_t stream) {
    const float* expr = (const float*)d_in[0];
    // d_in[1] = audio_features: unused by the reference
    const float* uv   = (const float*)d_in[2];
    const float* data = (const float*)d_in[3];
    const float* W1   = (const float*)d_in[4];
    const float* b1   = (const float*)d_in[5];
    const float* W2   = (const float*)d_in[6];
    const float* b2   = (const float*)d_in[7];
    const float* W3   = (const float*)d_in[8];
    const float* b3   = (const float*)d_in[9];
    float* out = (float*)d_out;

    float* filt_t = (float*)d_ws;                          // 8192 floats = 32 KB
    unsigned short* tex = (unsigned short*)((char*)d_ws + 32768); // TD*TD*16 bf16

    mlp_kernel<<<32, 256, 0, stream>>>(expr, W1, b1, W2, b2, W3, b3, filt_t);
    conv_kernel<<<dim3((TD + 63) / 64, (TD + 3) / 4), dim3(64, 4), 0, stream>>>(
        data, filt_t, tex);
    sample_kernel<<<NPX / 256, 256, 0, stream>>>(uv, tex, out);
}

// Round 2
// 498.987 us; speedup vs baseline: 1.9719x; 1.9719x over previous
//
#include <hip/hip_runtime.h>
#include <math.h>

// Problem constants
#define NPX   1048576      // 1024*1024
#define TD    1025         // tex_eval spatial dim
// ws layout: [0, 32KB)        filt_t  fp32 [k][oc]  (k = ic*16 + ky*4 + kx)
//            [32KB, 48KB)     ffrag_g fp16 [kk][lane][8]  (MFMA B-fragment order)
//            [48KB, ..)       tex     bf16 [y][x][c], (TD*TD*16)

typedef _Float16 half8 __attribute__((ext_vector_type(8)));
typedef float    f32x4 __attribute__((ext_vector_type(4)));

__device__ __forceinline__ unsigned short f2bf(float f) {
    unsigned u = __float_as_uint(f);
    unsigned r = (u + 0x7fffu + ((u >> 16) & 1u)) >> 16;
    return (unsigned short)r;
}
__device__ __forceinline__ float bf2f(unsigned short s) {
    return __uint_as_float((unsigned)s << 16);
}

// ---------------- Stage 1: MLP -> conv filter (transposed layout) -------------
__global__ __launch_bounds__(256) void mlp_kernel(
    const float* __restrict__ expr,
    const float* __restrict__ W1, const float* __restrict__ b1,
    const float* __restrict__ W2, const float* __restrict__ b2,
    const float* __restrict__ W3, const float* __restrict__ b3,
    float* __restrict__ filt_t)
{
    __shared__ float sx[76];
    __shared__ float sh1[128];
    __shared__ float sh2[64];
    int t = threadIdx.x;
    if (t < 76) sx[t] = expr[t];
    __syncthreads();
    if (t < 128) {
        float a = b1[t];
        const float* w = W1 + t * 76;
        #pragma unroll 4
        for (int i = 0; i < 76; ++i) a += sx[i] * w[i];
        sh1[t] = a >= 0.f ? a : 0.02f * a;
    }
    __syncthreads();
    if (t < 64) {
        float a = b2[t];
        const float* w = W2 + t * 128;
        #pragma unroll 4
        for (int i = 0; i < 128; ++i) a += sh1[i] * w[i];
        sh2[t] = a >= 0.f ? a : 0.02f * a;
    }
    __syncthreads();
    int o = blockIdx.x * 256 + t;            // 0..8191
    float a = b3[o];
    const float* w = W3 + o * 64;
    #pragma unroll 4
    for (int i = 0; i < 64; ++i) a += sh2[i] * w[i];
    a = tanhf(a);
    int oc = o >> 9;                          // o / 512
    int k  = o & 511;                         // ic*16 + ky*4 + kx
    filt_t[k * 16 + oc] = a;
}

// ------------- Stage 1b: build MFMA B-fragment-ordered filter (fp16) ---------
// ffrag_g[kk][lane][j] = f16( filt_t[(ic*16 + kk)*16 + oc] ),
//   ic = (lane>>4)*8 + j, oc = lane&15, kk = ky*4+kx
__global__ __launch_bounds__(256) void ffrag_kernel(
    const float* __restrict__ filt_t, _Float16* __restrict__ ffrag_g)
{
    int idx = blockIdx.x * 256 + threadIdx.x;  // 0..1023 (grid = 4)
    int kk = idx >> 6;
    int l  = idx & 63;
    int q  = l >> 4, oc = l & 15;
    half8 h;
    #pragma unroll
    for (int j = 0; j < 8; ++j) {
        int ic = q * 8 + j;
        h[j] = (_Float16)filt_t[(ic * 16 + kk) * 16 + oc];
    }
    *(half8*)&ffrag_g[idx * 8] = h;
}

// ------------- Stage 2: implicit-GEMM conv via 16x16x32 f16 MFMA -------------
// Tile per workgroup: 32(x) x 16(y) output pixels. Patch: 35 x 19 cells x 32 ic.
// Decomposition: 16 shifted 1x1 convs (kk = ky*4+kx), K = ic (32) per MFMA.
#define PW 35
#define PH 19
#define NCELL (PW * PH)   // 665

__global__ __launch_bounds__(256, 2) void conv_mfma_kernel(
    const float* __restrict__ data,          // [32][1024][1024] fp32
    const _Float16* __restrict__ ffrag_g,    // [16][64][8] fp16
    unsigned short* __restrict__ tex)        // [1025][1025][16] bf16
{
    __shared__ _Float16 sp[NCELL * 32];      // 42,560 B channel-last patch
    __shared__ _Float16 ffr[16 * 512];       // 16,384 B filter fragments

    int tid = threadIdx.x;
    int ox0 = blockIdx.x * 32;
    int oy0 = blockIdx.y * 16;

    // stage filter fragments (16 KB, L2-hot)
    {
        const uint4* src = (const uint4*)ffrag_g;
        uint4* dst = (uint4*)ffr;
        #pragma unroll
        for (int i = 0; i < 4; ++i) dst[tid + i * 256] = src[tid + i * 256];
    }

    // stage patch: one thread per cell, 32 ics -> fp16 channel-last
    for (int c = tid; c < NCELL; c += 256) {
        int y = c / PW;
        int x = c - y * PW;
        int yy = oy0 - 2 + y;
        int xx = ox0 - 2 + x;
        bool ok = ((unsigned)yy < 1024u) && ((unsigned)xx < 1024u);
        const float* dp = data + ((size_t)yy * 1024 + xx);
        #pragma unroll
        for (int qq = 0; qq < 4; ++qq) {
            half8 h;
            #pragma unroll
            for (int j = 0; j < 8; ++j) {
                float v = ok ? dp[(size_t)(qq * 8 + j) * NPX] : 0.0f;
                h[j] = (_Float16)v;
            }
            *(half8*)&sp[c * 32 + qq * 8] = h;
        }
    }
    __syncthreads();

    int l = tid & 63;
    int w = tid >> 6;          // wave id: rows w*4 .. w*4+3 of the tile
    int lane15 = l & 15;
    int q = l >> 4;

    f32x4 acc[8];
    #pragma unroll
    for (int t = 0; t < 8; ++t) acc[t] = (f32x4){0.f, 0.f, 0.f, 0.f};

    // m-tile t: tile row (w*4 + (t>>1)), x half (t&1); lane pixel = lane15
    #pragma unroll 4
    for (int kk = 0; kk < 16; ++kk) {
        int ky = kk >> 2, kx = kk & 3;
        half8 bf = *(half8*)&ffr[kk * 512 + l * 8];
        #pragma unroll
        for (int t = 0; t < 8; ++t) {
            int pc = (w * 4 + (t >> 1) + ky) * PW + (t & 1) * 16 + lane15 + kx;
            half8 af = *(half8*)&sp[pc * 32 + q * 8];
            acc[t] = __builtin_amdgcn_mfma_f32_16x16x32_f16(af, bf, acc[t], 0, 0, 0);
        }
    }

    // epilogue: C/D layout col = lane&15 (oc), row = q*4 + reg (pixel in m-tile)
    #pragma unroll
    for (int t = 0; t < 8; ++t) {
        int oy = oy0 + w * 4 + (t >> 1);
        if (oy > 1024) continue;
        int pxb = ox0 + (t & 1) * 16 + q * 4;
        #pragma unroll
        for (int r = 0; r < 4; ++r) {
            int px = pxb + r;
            if (px > 1024) continue;
            tex[((size_t)oy * TD + px) * 16 + lane15] = f2bf(acc[t][r]);
        }
    }
}

// ---------------- Stage 3: bilinear grid-sample (border pad) -----------------
__global__ __launch_bounds__(256) void sample_kernel(
    const float* __restrict__ uv,            // [2][1024][1024]
    const unsigned short* __restrict__ tex,  // [1025][1025][16] bf16
    float* __restrict__ out)                 // [16][1024][1024]
{
    int p = blockIdx.x * 256 + threadIdx.x;  // 0..NPX-1
    float x = uv[p];
    float y = uv[NPX + p];
    float ix = ((x + 1.0f) * 1025.0f - 1.0f) * 0.5f;
    float iy = ((y + 1.0f) * 1025.0f - 1.0f) * 0.5f;
    ix = fminf(fmaxf(ix, 0.0f), 1024.0f);
    iy = fminf(fmaxf(iy, 0.0f), 1024.0f);
    float fx0 = floorf(ix), fy0 = floorf(iy);
    float wx = ix - fx0, wy = iy - fy0;
    int x0 = (int)fx0, y0 = (int)fy0;
    int x1 = min(x0 + 1, 1024), y1 = min(y0 + 1, 1024);

    const uint4* t00 = (const uint4*)(tex + (size_t)(y0 * TD + x0) * 16);
    const uint4* t01 = (const uint4*)(tex + (size_t)(y0 * TD + x1) * 16);
    const uint4* t10 = (const uint4*)(tex + (size_t)(y1 * TD + x0) * 16);
    const uint4* t11 = (const uint4*)(tex + (size_t)(y1 * TD + x1) * 16);

    float w00 = (1.f - wx) * (1.f - wy);
    float w01 = wx * (1.f - wy);
    float w10 = (1.f - wx) * wy;
    float w11 = wx * wy;

    #pragma unroll
    for (int h = 0; h < 2; ++h) {
        uint4 a = t00[h], b = t01[h], c = t10[h], d = t11[h];
        const unsigned* au = (const unsigned*)&a;
        const unsigned* bu = (const unsigned*)&b;
        const unsigned* cu = (const unsigned*)&c;
        const unsigned* du = (const unsigned*)&d;
        #pragma unroll
        for (int qq = 0; qq < 4; ++qq) {
            float a0 = bf2f((unsigned short)(au[qq] & 0xffffu));
            float a1 = bf2f((unsigned short)(au[qq] >> 16));
            float b0 = bf2f((unsigned short)(bu[qq] & 0xffffu));
            float b1 = bf2f((unsigned short)(bu[qq] >> 16));
            float c0 = bf2f((unsigned short)(cu[qq] & 0xffffu));
            float c1 = bf2f((unsigned short)(cu[qq] >> 16));
            float d0 = bf2f((unsigned short)(du[qq] & 0xffffu));
            float d1 = bf2f((unsigned short)(du[qq] >> 16));
            int ch = h * 8 + qq * 2;
            float r0 = a0 * w00 + b0 * w01 + c0 * w10 + d0 * w11;
            float r1 = a1 * w00 + b1 * w01 + c1 * w10 + d1 * w11;
            out[(size_t)ch * NPX + p]       = r0;
            out[(size_t)(ch + 1) * NPX + p] = r1;
        }
    }
}

extern "C" void kernel_launch(void* const* d_in, const int* in_sizes, int n_in,
                              void* d_out, int out_size, void* d_ws, size_t ws_size,
                              hipStream_t stream) {
    const float* expr = (const float*)d_in[0];
    // d_in[1] = audio_features: unused by the reference
    const float* uv   = (const float*)d_in[2];
    const float* data = (const float*)d_in[3];
    const float* W1   = (const float*)d_in[4];
    const float* b1   = (const float*)d_in[5];
    const float* W2   = (const float*)d_in[6];
    const float* b2   = (const float*)d_in[7];
    const float* W3   = (const float*)d_in[8];
    const float* b3   = (const float*)d_in[9];
    float* out = (float*)d_out;

    float* filt_t      = (float*)d_ws;                               // 32 KB
    _Float16* ffrag_g  = (_Float16*)((char*)d_ws + 32768);           // 16 KB
    unsigned short* tex = (unsigned short*)((char*)d_ws + 49152);    // 33.62 MB

    mlp_kernel<<<32, 256, 0, stream>>>(expr, W1, b1, W2, b2, W3, b3, filt_t);
    ffrag_kernel<<<4, 256, 0, stream>>>(filt_t, ffrag_g);
    conv_mfma_kernel<<<dim3(33, 65), 256, 0, stream>>>(data, ffrag_g, tex);
    sample_kernel<<<NPX / 256, 256, 0, stream>>>(uv, tex, out);
}

// Round 3
// 389.711 us; speedup vs baseline: 2.5248x; 1.2804x over previous
//
#include <hip/hip_runtime.h>
#include <math.h>

// Problem constants
#define NPX   1048576      // 1024*1024
#define TD    1025         // tex_eval spatial dim
#define PW    35           // patch width (cells) for 32-wide tile
#define PH    19           // patch height (cells) for 16-tall tile
#define DPAD  1028         // padded input spatial dim (rows -2..1025 -> 0..1027)
#define ROWB  65792        // DPAD*32*2 bytes per padded row
// ws layout: [0, 32KB)            filt_t  fp32 [k][oc] (k = ic*16 + ky*4 + kx)
//            [32KB, 48KB)         ffrag_g fp16 [kk][lane][8] (MFMA B-frag order)
//            [48KB, +33.62MB)     tex     fp16 [y][x][c]  (TD*TD*16)
//            [DP_OFF, +67.63MB)   Dp      fp16 [1028][1028][32] zero-padded CL
#define DP_OFF 33673216

typedef _Float16 half8 __attribute__((ext_vector_type(8)));
typedef float    f32x4 __attribute__((ext_vector_type(4)));

__device__ __forceinline__ void load_lds16(const void* g, void* lds) {
    __builtin_amdgcn_global_load_lds(
        (const __attribute__((address_space(1))) void*)g,
        (__attribute__((address_space(3))) void*)lds, 16, 0, 0);
}

// ---------------- Stage 1: MLP -> conv filter (transposed layout) -------------
__global__ __launch_bounds__(256) void mlp_kernel(
    const float* __restrict__ expr,
    const float* __restrict__ W1, const float* __restrict__ b1,
    const float* __restrict__ W2, const float* __restrict__ b2,
    const float* __restrict__ W3, const float* __restrict__ b3,
    float* __restrict__ filt_t)
{
    __shared__ float sx[76];
    __shared__ float sh1[128];
    __shared__ float sh2[64];
    int t = threadIdx.x;
    if (t < 76) sx[t] = expr[t];
    __syncthreads();
    if (t < 128) {
        float a = b1[t];
        const float* w = W1 + t * 76;
        #pragma unroll 4
        for (int i = 0; i < 76; ++i) a += sx[i] * w[i];
        sh1[t] = a >= 0.f ? a : 0.02f * a;
    }
    __syncthreads();
    if (t < 64) {
        float a = b2[t];
        const float* w = W2 + t * 128;
        #pragma unroll 4
        for (int i = 0; i < 128; ++i) a += sh1[i] * w[i];
        sh2[t] = a >= 0.f ? a : 0.02f * a;
    }
    __syncthreads();
    int o = blockIdx.x * 256 + t;            // 0..8191
    float a = b3[o];
    const float* w = W3 + o * 64;
    #pragma unroll 4
    for (int i = 0; i < 64; ++i) a += sh2[i] * w[i];
    a = tanhf(a);
    int oc = o >> 9;                          // o / 512
    int k  = o & 511;                         // ic*16 + ky*4 + kx
    filt_t[k * 16 + oc] = a;
}

// ------------- Stage 1b: build MFMA B-fragment-ordered filter (fp16) ---------
// ffrag_g[kk][lane][j] = f16( filt_t[(ic*16 + kk)*16 + oc] ),
//   ic = (lane>>4)*8 + j, oc = lane&15, kk = ky*4+kx
__global__ __launch_bounds__(256) void ffrag_kernel(
    const float* __restrict__ filt_t, _Float16* __restrict__ ffrag_g)
{
    int idx = blockIdx.x * 256 + threadIdx.x;  // 0..1023 (grid = 4)
    int kk = idx >> 6;
    int l  = idx & 63;
    int q  = l >> 4, oc = l & 15;
    half8 h;
    #pragma unroll
    for (int j = 0; j < 8; ++j) {
        int ic = q * 8 + j;
        h[j] = (_Float16)filt_t[(ic * 16 + kk) * 16 + oc];
    }
    *(half8*)&ffrag_g[idx * 8] = h;
}

// ------ Stage 1c: repack data fp32 NCHW -> zero-padded fp16 channel-last -----
// Dp[Y][X][ic], Y = y+2, X = x+2, zeros outside [0,1024). Fully coalesced via
// XOR-swizzled LDS transpose (conflict-free writes AND reads).
__global__ __launch_bounds__(256) void repack_kernel(
    const float* __restrict__ data, _Float16* __restrict__ Dp)
{
    __shared__ _Float16 s[256 * 32];          // 16 KB
    int tid = threadIdx.x;
    int Y = blockIdx.y;
    int X = blockIdx.x * 256 + tid;
    int y = Y - 2, x = X - 2;
    bool ok = ((unsigned)y < 1024u) && ((unsigned)x < 1024u);
    const float* dp = data + ((size_t)y << 10) + x;

    float v[32];
    #pragma unroll
    for (int j = 0; j < 32; ++j) v[j] = 0.f;
    if (ok) {
        #pragma unroll
        for (int j = 0; j < 32; ++j) v[j] = dp[(size_t)j * NPX];
    }
    #pragma unroll
    for (int g = 0; g < 4; ++g) {
        half8 h;
        #pragma unroll
        for (int j = 0; j < 8; ++j) h[j] = (_Float16)v[g * 8 + j];
        int chunk = tid * 4 + g;
        int sw = chunk ^ ((chunk >> 3) & 7);  // spread banks
        *(half8*)((char*)s + sw * 16) = h;
    }
    __syncthreads();
    char* rowbase = (char*)Dp + (size_t)Y * ROWB + blockIdx.x * 16384;
    int lim = ROWB - blockIdx.x * 16384;
    #pragma unroll
    for (int i = 0; i < 4; ++i) {
        int off = tid * 16 + i * 4096;
        if (off < lim) {
            int chunk = tid + i * 256;
            int sw = chunk ^ ((chunk >> 3) & 7);
            *(uint4*)(rowbase + off) = *(uint4*)((char*)s + sw * 16);
        }
    }
}

// ------------- Stage 2: implicit-GEMM conv via 16x16x32 f16 MFMA -------------
// Tile 32(x) x 16(y). Patch rows DMA'd via global_load_lds (contiguous 2240 B
// runs in channel-last Dp). Filter B-fragments live in registers.
__global__ __launch_bounds__(256, 3) void conv_mfma_kernel(
    const _Float16* __restrict__ Dp,         // [1028][1028][32] fp16
    const _Float16* __restrict__ ffrag_g,    // [16][64][8] fp16
    _Float16* __restrict__ tex)              // [1025][1025][16] fp16
{
    __shared__ _Float16 sp[PH * PW * 32];    // 42,560 B

    int tid = threadIdx.x;
    int l = tid & 63, w = tid >> 6;
    int ox0 = blockIdx.x * 32;
    int oy0 = blockIdx.y * 16;

    // filter fragments -> registers (64 VGPR), L2-hot
    half8 bfrag[16];
    #pragma unroll
    for (int kk = 0; kk < 16; ++kk)
        bfrag[kk] = *(const half8*)&ffrag_g[kk * 512 + l * 8];

    // stage patch: wave w DMAs rows w, w+4, ... ; 2240 B per row as 1024+1024+192.
    // Edge tiles: clamp the GLOBAL source address only — garbage lands in patch
    // cells consumed solely by discarded (oy/px > 1024) outputs.
    for (int r = w; r < PH; r += 4) {
        int gy = min(oy0 + r, DPAD - 1);
        const char* grow = (const char*)Dp + (size_t)gy * ROWB;
        _Float16* lrow = sp + r * (PW * 32);
        #pragma unroll
        for (int c = 0; c < 3; ++c) {
            int off = ox0 * 64 + c * 1024 + l * 16;
            off = min(off, ROWB - 16);
            if (c < 2 || l < 12)
                load_lds16(grow + off, (char*)lrow + c * 1024);
        }
    }
    __syncthreads();

    int lane15 = l & 15;
    int q = l >> 4;

    f32x4 acc[8];
    #pragma unroll
    for (int t = 0; t < 8; ++t) acc[t] = (f32x4){0.f, 0.f, 0.f, 0.f};

    // m-tile t: tile row (w*4 + (t>>1)), x half (t&1); lane pixel = lane15
    #pragma unroll 4
    for (int kk = 0; kk < 16; ++kk) {
        int ky = kk >> 2, kx = kk & 3;
        #pragma unroll
        for (int t = 0; t < 8; ++t) {
            int pc = (w * 4 + (t >> 1) + ky) * PW + (t & 1) * 16 + lane15 + kx;
            half8 af = *(half8*)&sp[pc * 32 + q * 8];
            acc[t] = __builtin_amdgcn_mfma_f32_16x16x32_f16(af, bfrag[kk], acc[t], 0, 0, 0);
        }
    }

    // epilogue: C/D layout col = lane&15 (oc), row = q*4 + reg (pixel in m-tile)
    #pragma unroll
    for (int t = 0; t < 8; ++t) {
        int oy = oy0 + w * 4 + (t >> 1);
        if (oy > 1024) continue;
        int pxb = ox0 + (t & 1) * 16 + q * 4;
        #pragma unroll
        for (int r = 0; r < 4; ++r) {
            int px = pxb + r;
            if (px > 1024) continue;
            tex[((size_t)oy * TD + px) * 16 + lane15] = (_Float16)acc[t][r];
        }
    }
}

// ---------------- Stage 3: bilinear grid-sample (border pad) -----------------
// 2 pixels per thread; all 16 texel loads issued before any use (max MLP).
__global__ __launch_bounds__(256) void sample_kernel(
    const float* __restrict__ uv,            // [2][1024][1024]
    const _Float16* __restrict__ tex,        // [1025][1025][16] fp16
    float* __restrict__ out)                 // [16][1024][1024]
{
    int p0 = blockIdx.x * 512 + threadIdx.x;
    half8 v[2][8];
    float W[2][4];
    #pragma unroll
    for (int i = 0; i < 2; ++i) {
        int p = p0 + i * 256;
        float x = uv[p], y = uv[NPX + p];
        float ix = fminf(fmaxf(((x + 1.f) * 1025.f - 1.f) * 0.5f, 0.f), 1024.f);
        float iy = fminf(fmaxf(((y + 1.f) * 1025.f - 1.f) * 0.5f, 0.f), 1024.f);
        float fx0 = floorf(ix), fy0 = floorf(iy);
        float wx = ix - fx0, wy = iy - fy0;
        int x0 = (int)fx0, y0 = (int)fy0;
        int x1 = min(x0 + 1, 1024), y1 = min(y0 + 1, 1024);
        const half8* t00 = (const half8*)(tex + ((size_t)y0 * TD + x0) * 16);
        const half8* t01 = (const half8*)(tex + ((size_t)y0 * TD + x1) * 16);
        const half8* t10 = (const half8*)(tex + ((size_t)y1 * TD + x0) * 16);
        const half8* t11 = (const half8*)(tex + ((size_t)y1 * TD + x1) * 16);
        v[i][0] = t00[0]; v[i][1] = t00[1];
        v[i][2] = t01[0]; v[i][3] = t01[1];
        v[i][4] = t10[0]; v[i][5] = t10[1];
        v[i][6] = t11[0]; v[i][7] = t11[1];
        W[i][0] = (1.f - wx) * (1.f - wy);
        W[i][1] = wx * (1.f - wy);
        W[i][2] = (1.f - wx) * wy;
        W[i][3] = wx * wy;
    }
    #pragma unroll
    for (int i = 0; i < 2; ++i) {
        int p = p0 + i * 256;
        #pragma unroll
        for (int h = 0; h < 2; ++h) {
            #pragma unroll
            for (int c = 0; c < 8; ++c) {
                float r = (float)v[i][0 + h][c] * W[i][0]
                        + (float)v[i][2 + h][c] * W[i][1]
                        + (float)v[i][4 + h][c] * W[i][2]
                        + (float)v[i][6 + h][c] * W[i][3];
                out[(size_t)(h * 8 + c) * NPX + p] = r;
            }
        }
    }
}

extern "C" void kernel_launch(void* const* d_in, const int* in_sizes, int n_in,
                              void* d_out, int out_size, void* d_ws, size_t ws_size,
                              hipStream_t stream) {
    const float* expr = (const float*)d_in[0];
    // d_in[1] = audio_features: unused by the reference
    const float* uv   = (const float*)d_in[2];
    const float* data = (const float*)d_in[3];
    const float* W1   = (const float*)d_in[4];
    const float* b1   = (const float*)d_in[5];
    const float* W2   = (const float*)d_in[6];
    const float* b2   = (const float*)d_in[7];
    const float* W3   = (const float*)d_in[8];
    const float* b3   = (const float*)d_in[9];
    float* out = (float*)d_out;

    float* filt_t      = (float*)d_ws;                               // 32 KB
    _Float16* ffrag_g  = (_Float16*)((char*)d_ws + 32768);           // 16 KB
    _Float16* tex      = (_Float16*)((char*)d_ws + 49152);           // 33.62 MB
    _Float16* Dp       = (_Float16*)((char*)d_ws + DP_OFF);          // 67.63 MB

    mlp_kernel<<<32, 256, 0, stream>>>(expr, W1, b1, W2, b2, W3, b3, filt_t);
    ffrag_kernel<<<4, 256, 0, stream>>>(filt_t, ffrag_g);
    repack_kernel<<<dim3(5, DPAD), 256, 0, stream>>>(data, Dp);
    conv_mfma_kernel<<<dim3(33, 65), 256, 0, stream>>>(Dp, ffrag_g, tex);
    sample_kernel<<<NPX / 512, 256, 0, stream>>>(uv, tex, out);
}

// Round 4
// 362.434 us; speedup vs baseline: 2.7148x; 1.0753x over previous
//
#include <hip/hip_runtime.h>
#include <math.h>

// Problem constants
#define NPX   1048576      // 1024*1024
#define TD    1025         // tex_eval spatial dim
#define PW    35           // patch width (cells) for 32-wide tile
#define PH    19           // patch height (cells) for 16-tall tile
#define DPAD  1028         // padded input spatial dim (rows -2..1025 -> 0..1027)
#define ROWB  65792        // DPAD*32*2 bytes per padded row
// ws layout: [0, 16KB)            ffrag_g fp16 [kk][lane][8] (MFMA B-frag order)
//            [48KB, +33.62MB)     tex     fp16 [y][x][c]  (TD*TD*16)
//            [DP_OFF, +67.63MB)   Dp      fp16 [1028][1028][32] zero-padded CL
#define DP_OFF 33673216

typedef _Float16 half8 __attribute__((ext_vector_type(8)));
typedef float    f32x4 __attribute__((ext_vector_type(4)));

__device__ __forceinline__ void load_lds16(const void* g, void* lds) {
    __builtin_amdgcn_global_load_lds(
        (const __attribute__((address_space(1))) void*)g,
        (__attribute__((address_space(3))) void*)lds, 16, 0, 0);
}

// ------- Stage 1: MLP -> MFMA B-fragment-ordered fp16 filter (fused) ---------
// Each of 32 blocks redundantly computes layers 1-2 (tiny), then its 256
// layer-3 outputs, writing each tanh directly into MFMA B-fragment order:
// ffrag_g[(kk*64 + (ic>>3)*16 + oc)*8 + (ic&7)],  o = oc*512 + ic*16 + kk.
__global__ __launch_bounds__(256) void mlp_kernel(
    const float* __restrict__ expr,
    const float* __restrict__ W1, const float* __restrict__ b1,
    const float* __restrict__ W2, const float* __restrict__ b2,
    const float* __restrict__ W3, const float* __restrict__ b3,
    _Float16* __restrict__ ffrag_g)
{
    __shared__ float sx[76];
    __shared__ float sh1[128];
    __shared__ float sh2[64];
    int t = threadIdx.x;
    if (t < 76) sx[t] = expr[t];
    __syncthreads();
    if (t < 128) {
        float a = b1[t];
        const float* w = W1 + t * 76;
        #pragma unroll 4
        for (int i = 0; i < 76; ++i) a += sx[i] * w[i];
        sh1[t] = a >= 0.f ? a : 0.02f * a;
    }
    __syncthreads();
    if (t < 64) {
        float a = b2[t];
        const float* w = W2 + t * 128;
        #pragma unroll 4
        for (int i = 0; i < 128; ++i) a += sh1[i] * w[i];
        sh2[t] = a >= 0.f ? a : 0.02f * a;
    }
    __syncthreads();
    int o = blockIdx.x * 256 + t;            // 0..8191
    float a = b3[o];
    const float* w = W3 + o * 64;
    #pragma unroll 4
    for (int i = 0; i < 64; ++i) a += sh2[i] * w[i];
    a = tanhf(a);
    int oc = o >> 9;                          // o / 512
    int ic = (o >> 4) & 31;
    int kk = o & 15;                          // ky*4+kx
    ffrag_g[(size_t)(kk * 64 + (ic >> 3) * 16 + oc) * 8 + (ic & 7)] = (_Float16)a;
}

// ------ Stage 1c: repack data fp32 NCHW -> zero-padded fp16 channel-last -----
// Dp[Y][X][ic], Y = y+2, X = x+2, zeros outside [0,1024). Fully coalesced via
// XOR-swizzled LDS transpose (conflict-free writes AND reads).
__global__ __launch_bounds__(256) void repack_kernel(
    const float* __restrict__ data, _Float16* __restrict__ Dp)
{
    __shared__ _Float16 s[256 * 32];          // 16 KB
    int tid = threadIdx.x;
    int Y = blockIdx.y;
    int X = blockIdx.x * 256 + tid;
    int y = Y - 2, x = X - 2;
    bool ok = ((unsigned)y < 1024u) && ((unsigned)x < 1024u);
    const float* dp = data + ((size_t)y << 10) + x;

    float v[32];
    #pragma unroll
    for (int j = 0; j < 32; ++j) v[j] = 0.f;
    if (ok) {
        #pragma unroll
        for (int j = 0; j < 32; ++j) v[j] = __builtin_nontemporal_load(&dp[(size_t)j * NPX]);
    }
    #pragma unroll
    for (int g = 0; g < 4; ++g) {
        half8 h;
        #pragma unroll
        for (int j = 0; j < 8; ++j) h[j] = (_Float16)v[g * 8 + j];
        int chunk = tid * 4 + g;
        int sw = chunk ^ ((chunk >> 3) & 7);  // spread banks
        *(half8*)((char*)s + sw * 16) = h;
    }
    __syncthreads();
    char* rowbase = (char*)Dp + (size_t)Y * ROWB + blockIdx.x * 16384;
    int lim = ROWB - blockIdx.x * 16384;
    #pragma unroll
    for (int i = 0; i < 4; ++i) {
        int off = tid * 16 + i * 4096;
        if (off < lim) {
            int chunk = tid + i * 256;
            int sw = chunk ^ ((chunk >> 3) & 7);
            *(uint4*)(rowbase + off) = *(uint4*)((char*)s + sw * 16);
        }
    }
}

// ------------- Stage 2: implicit-GEMM conv via 16x16x32 f16 MFMA -------------
// Tile 32(x) x 16(y). Patch rows DMA'd via global_load_lds (contiguous 2240 B
// runs in channel-last Dp). Filter B-fragments live in registers.
__global__ __launch_bounds__(256, 3) void conv_mfma_kernel(
    const _Float16* __restrict__ Dp,         // [1028][1028][32] fp16
    const _Float16* __restrict__ ffrag_g,    // [16][64][8] fp16
    _Float16* __restrict__ tex)              // [1025][1025][16] fp16
{
    __shared__ _Float16 sp[PH * PW * 32];    // 42,560 B

    int tid = threadIdx.x;
    int l = tid & 63, w = tid >> 6;
    int ox0 = blockIdx.x * 32;
    int oy0 = blockIdx.y * 16;

    // filter fragments -> registers (64 VGPR), L2-hot
    half8 bfrag[16];
    #pragma unroll
    for (int kk = 0; kk < 16; ++kk)
        bfrag[kk] = *(const half8*)&ffrag_g[kk * 512 + l * 8];

    // stage patch: wave w DMAs rows w, w+4, ... ; 2240 B per row as 1024+1024+192.
    // Edge tiles: clamp the GLOBAL source address only — garbage lands in patch
    // cells consumed solely by discarded (oy/px > 1024) outputs.
    for (int r = w; r < PH; r += 4) {
        int gy = min(oy0 + r, DPAD - 1);
        const char* grow = (const char*)Dp + (size_t)gy * ROWB;
        _Float16* lrow = sp + r * (PW * 32);
        #pragma unroll
        for (int c = 0; c < 3; ++c) {
            int off = ox0 * 64 + c * 1024 + l * 16;
            off = min(off, ROWB - 16);
            if (c < 2 || l < 12)
                load_lds16(grow + off, (char*)lrow + c * 1024);
        }
    }
    __syncthreads();

    int lane15 = l & 15;
    int q = l >> 4;

    f32x4 acc[8];
    #pragma unroll
    for (int t = 0; t < 8; ++t) acc[t] = (f32x4){0.f, 0.f, 0.f, 0.f};

    // m-tile t: tile row (w*4 + (t>>1)), x half (t&1); lane pixel = lane15
    #pragma unroll 4
    for (int kk = 0; kk < 16; ++kk) {
        int ky = kk >> 2, kx = kk & 3;
        #pragma unroll
        for (int t = 0; t < 8; ++t) {
            int pc = (w * 4 + (t >> 1) + ky) * PW + (t & 1) * 16 + lane15 + kx;
            half8 af = *(half8*)&sp[pc * 32 + q * 8];
            acc[t] = __builtin_amdgcn_mfma_f32_16x16x32_f16(af, bfrag[kk], acc[t], 0, 0, 0);
        }
    }

    // epilogue: C/D layout col = lane&15 (oc), row = q*4 + reg (pixel in m-tile)
    #pragma unroll
    for (int t = 0; t < 8; ++t) {
        int oy = oy0 + w * 4 + (t >> 1);
        if (oy > 1024) continue;
        int pxb = ox0 + (t & 1) * 16 + q * 4;
        #pragma unroll
        for (int r = 0; r < 4; ++r) {
            int px = pxb + r;
            if (px > 1024) continue;
            tex[((size_t)oy * TD + px) * 16 + lane15] = (_Float16)acc[t][r];
        }
    }
}

// ---------------- Stage 3: bilinear grid-sample (border pad) -----------------
// 1 px/thread, minimal VGPR -> max resident waves (gather-latency hiding).
// All 8 texel loads issued before any use; nontemporal uv/out (stream-once).
__global__ __launch_bounds__(256, 6) void sample_kernel(
    const float* __restrict__ uv,            // [2][1024][1024]
    const _Float16* __restrict__ tex,        // [1025][1025][16] fp16
    float* __restrict__ out)                 // [16][1024][1024]
{
    int p = blockIdx.x * 256 + threadIdx.x;  // 0..NPX-1
    float x = __builtin_nontemporal_load(&uv[p]);
    float y = __builtin_nontemporal_load(&uv[NPX + p]);
    float ix = fminf(fmaxf(((x + 1.f) * 1025.f - 1.f) * 0.5f, 0.f), 1024.f);
    float iy = fminf(fmaxf(((y + 1.f) * 1025.f - 1.f) * 0.5f, 0.f), 1024.f);
    float fx0 = floorf(ix), fy0 = floorf(iy);
    float wx = ix - fx0, wy = iy - fy0;
    int x0 = (int)fx0, y0 = (int)fy0;
    int x1 = min(x0 + 1, 1024), y1 = min(y0 + 1, 1024);

    const half8* t00 = (const half8*)(tex + ((size_t)y0 * TD + x0) * 16);
    const half8* t01 = (const half8*)(tex + ((size_t)y0 * TD + x1) * 16);
    const half8* t10 = (const half8*)(tex + ((size_t)y1 * TD + x0) * 16);
    const half8* t11 = (const half8*)(tex + ((size_t)y1 * TD + x1) * 16);

    half8 v0 = t00[0], v1 = t00[1];
    half8 v2 = t01[0], v3 = t01[1];
    half8 v4 = t10[0], v5 = t10[1];
    half8 v6 = t11[0], v7 = t11[1];

    float w00 = (1.f - wx) * (1.f - wy);
    float w01 = wx * (1.f - wy);
    float w10 = (1.f - wx) * wy;
    float w11 = wx * wy;

    #pragma unroll
    for (int c = 0; c < 8; ++c) {
        float r0 = (float)v0[c] * w00 + (float)v2[c] * w01
                 + (float)v4[c] * w10 + (float)v6[c] * w11;
        float r1 = (float)v1[c] * w00 + (float)v3[c] * w01
                 + (float)v5[c] * w10 + (float)v7[c] * w11;
        __builtin_nontemporal_store(r0, &out[(size_t)c * NPX + p]);
        __builtin_nontemporal_store(r1, &out[(size_t)(c + 8) * NPX + p]);
    }
}

extern "C" void kernel_launch(void* const* d_in, const int* in_sizes, int n_in,
                              void* d_out, int out_size, void* d_ws, size_t ws_size,
                              hipStream_t stream) {
    const float* expr = (const float*)d_in[0];
    // d_in[1] = audio_features: unused by the reference
    const float* uv   = (const float*)d_in[2];
    const float* data = (const float*)d_in[3];
    const float* W1   = (const float*)d_in[4];
    const float* b1   = (const float*)d_in[5];
    const float* W2   = (const float*)d_in[6];
    const float* b2   = (const float*)d_in[7];
    const float* W3   = (const float*)d_in[8];
    const float* b3   = (const float*)d_in[9];
    float* out = (float*)d_out;

    _Float16* ffrag_g  = (_Float16*)d_ws;                            // 16 KB
    _Float16* tex      = (_Float16*)((char*)d_ws + 49152);           // 33.62 MB
    _Float16* Dp       = (_Float16*)((char*)d_ws + DP_OFF);          // 67.63 MB

    mlp_kernel<<<32, 256, 0, stream>>>(expr, W1, b1, W2, b2, W3, b3, ffrag_g);
    repack_kernel<<<dim3(5, DPAD), 256, 0, stream>>>(data, Dp);
    conv_mfma_kernel<<<dim3(33, 65), 256, 0, stream>>>(Dp, ffrag_g, tex);
    sample_kernel<<<NPX / 256, 256, 0, stream>>>(uv, tex, out);
}